// Round 13
// baseline (477.401 us; speedup 1.0000x reference)
//
#include <hip/hip_runtime.h>
#include <cstdint>
#include <cstddef>

#define MROWS 1024
#define NCOLS 4096
#define KCAP 8

typedef unsigned long long u64;
typedef unsigned int u32;

// Order-preserving float->u32 map (total order, matches score order exactly).
__device__ inline u32 fkey(u32 b) { return (b & 0x80000000u) ? ~b : (b | 0x80000000u); }

// key = (ord << 22) | ((1023-row) << 12) | (4095-col)   (54 bits used)
__device__ inline int key_col(u64 k) { return (NCOLS - 1) - (int)(k & 0xFFFull); }
__device__ inline int key_row(u64 k) { return (MROWS - 1) - (int)((k >> 12) & 0x3FFull); }

// single-wave LDS ordering fence: wait LDS only, do NOT drain vmcnt
#define WAVE_FENCE() __asm__ volatile("s_waitcnt lgkmcnt(0)" ::: "memory")

__device__ inline float wave_sum_f(float v) {
    #pragma unroll
    for (int off = 32; off >= 1; off >>= 1)
        v += __shfl_xor(v, off, 64);
    return v;
}
__device__ inline u64 wave_max_u64(u64 v) {
    #pragma unroll
    for (int off = 32; off >= 1; off >>= 1) {
        u64 o = __shfl_xor(v, off, 64);
        v = o > v ? o : v;
    }
    return v;
}
__device__ inline u64 umax64(u64 a, u64 b) { return a > b ? a : b; }

// ---------------- K1: per-row threshold key-set + exp-sum ---------------------
// Wave-per-row, ZERO block barriers, 256 workgroups (proven ~7us). {keys:
// score > T} is an exact prefix of the row's descending key order for any T
// (fkey monotone; ties cannot straddle T). Ladder 3.0/3.25/3.6/4.0 on overflow
// (count monotone in T; ~11% rows retry once, L2-hot reload). Short/empty
// prefix stays exact (row exhausts -> exact fallback in K2). E[count@3.0]~5.5.
__global__ __launch_bounds__(256, 4) void k_prep(const float* __restrict__ s,
                                                 float* __restrict__ rowsum,
                                                 u64* __restrict__ keys_g) {
    __shared__ u64 list[4][KCAP];
    __shared__ u32 cnts[4];
    int w = threadIdx.x >> 6, lane = threadIdx.x & 63;
    int r = blockIdx.x * 4 + w;

    const float4* s4 = (const float4*)(s + (size_t)r * NCOLS);
    u64 rowpart = (u64)(MROWS - 1 - r) << 12;
    if (lane == 0) cnts[w] = 0u;
    WAVE_FENCE();

    float acc = 0.0f;
    #pragma unroll
    for (int j = 0; j < 16; ++j) {
        float4 v = s4[lane + j * 64];
        acc += __expf(v.x) + __expf(v.y) + __expf(v.z) + __expf(v.w);
        int c0 = 4 * (lane + j * 64);
        if (v.x > 3.0f) { u32 sl = atomicAdd(&cnts[w], 1u); if (sl < KCAP)
            list[w][sl] = ((u64)fkey(__float_as_uint(v.x)) << 22) | rowpart | (u64)(NCOLS - 1 - (c0 + 0)); }
        if (v.y > 3.0f) { u32 sl = atomicAdd(&cnts[w], 1u); if (sl < KCAP)
            list[w][sl] = ((u64)fkey(__float_as_uint(v.y)) << 22) | rowpart | (u64)(NCOLS - 1 - (c0 + 1)); }
        if (v.z > 3.0f) { u32 sl = atomicAdd(&cnts[w], 1u); if (sl < KCAP)
            list[w][sl] = ((u64)fkey(__float_as_uint(v.z)) << 22) | rowpart | (u64)(NCOLS - 1 - (c0 + 2)); }
        if (v.w > 3.0f) { u32 sl = atomicAdd(&cnts[w], 1u); if (sl < KCAP)
            list[w][sl] = ((u64)fkey(__float_as_uint(v.w)) << 22) | rowpart | (u64)(NCOLS - 1 - (c0 + 3)); }
    }
    acc = wave_sum_f(acc);
    if (lane == 0) rowsum[r] = acc;
    WAVE_FENCE();
    u32 n = cnts[w];

    for (int att = 1; att < 5; ++att) {
        if (n <= KCAP) break;
        float T = att == 1 ? 3.25f : att == 2 ? 3.6f : 4.0f;
        if (lane == 0) cnts[w] = 0u;
        WAVE_FENCE();
        #pragma unroll 4
        for (int j = 0; j < 16; ++j) {
            float4 v = s4[lane + j * 64];
            int c0 = 4 * (lane + j * 64);
            if (v.x > T) { u32 sl = atomicAdd(&cnts[w], 1u); if (sl < KCAP)
                list[w][sl] = ((u64)fkey(__float_as_uint(v.x)) << 22) | rowpart | (u64)(NCOLS - 1 - (c0 + 0)); }
            if (v.y > T) { u32 sl = atomicAdd(&cnts[w], 1u); if (sl < KCAP)
                list[w][sl] = ((u64)fkey(__float_as_uint(v.y)) << 22) | rowpart | (u64)(NCOLS - 1 - (c0 + 1)); }
            if (v.z > T) { u32 sl = atomicAdd(&cnts[w], 1u); if (sl < KCAP)
                list[w][sl] = ((u64)fkey(__float_as_uint(v.z)) << 22) | rowpart | (u64)(NCOLS - 1 - (c0 + 2)); }
            if (v.w > T) { u32 sl = atomicAdd(&cnts[w], 1u); if (sl < KCAP)
                list[w][sl] = ((u64)fkey(__float_as_uint(v.w)) << 22) | rowpart | (u64)(NCOLS - 1 - (c0 + 3)); }
        }
        WAVE_FENCE();
        n = cnts[w];
    }
    if (n > KCAP) n = 0;               // ladder failed (adversarial): empty prefix
    if (lane < KCAP)
        keys_g[(size_t)r * KCAP + lane] = (lane < n) ? list[w][lane] : 0ull;
}

// ---------------- K2: block 0 = match (keys in LDS); rest = policy ------------
// The spill-proof match: per-row keys live in LDS (keybuf, read-only after
// load); per-thread state is an 8-bit alive MASK + a few scalars. No register
// arrays exist => the allocator cannot demote key state to scratch (the r9/
// r10/r12 416us failure mode: VGPR 88/60/24, monotone damage). Dominant-edge
// rounds, 512 threads x 2 rows; submit ALL alive keys (required for
// exactness); commit when row-best == col-best (keys distinct); colbest
// tagged by round so stale submissions auto-lose.
__global__ __launch_bounds__(512, 1) void k_policy_match(const float* __restrict__ s,
                                                         const int* __restrict__ cont,
                                                         const int* __restrict__ prev,
                                                         const float* __restrict__ rowsum,
                                                         const u64* __restrict__ keys_g,
                                                         float* __restrict__ policy,
                                                         float* __restrict__ actions) {
    __shared__ u64 keybuf[MROWS * KCAP];       // 64 KiB (match only, RO)
    __shared__ u64 colbest[NCOLS];             // 32 KiB (match only)
    __shared__ u32 coldone[NCOLS / 32];        // 512 B
    __shared__ u32 rowdone[MROWS / 32];        // 128 B
    __shared__ float act[MROWS];               // 4 KiB
    __shared__ u32 leftrows[64];
    __shared__ int nleft;
    __shared__ float fredf[8];

    int t = threadIdx.x;
    int wid = t >> 6, lane = t & 63;

    if (blockIdx.x != 0) {
        // ---------------- policy row write (512 thr, 2 float4/thr) ------------
        int r = blockIdx.x - 1;
        const float4* srow4 = (const float4*)(s + (size_t)r * NCOLS);
        float4 v0 = srow4[t], v1 = srow4[t + 512];   // fly during the reduce
        float sv = rowsum[t] + rowsum[t + 512];
        sv = wave_sum_f(sv);
        if (lane == 0) fredf[wid] = sv;
        __syncthreads();
        float g = 0.0f;
        #pragma unroll
        for (int i = 0; i < 8; ++i) g += fredf[i];   // same order every block
        float inv = 1.0f / g;
        float4* prow4 = (float4*)(policy + (size_t)r * NCOLS);
        float4 p;
        p.x = __expf(v0.x) * inv; p.y = __expf(v0.y) * inv;
        p.z = __expf(v0.z) * inv; p.w = __expf(v0.w) * inv;
        prow4[t] = p;
        p.x = __expf(v1.x) * inv; p.y = __expf(v1.y) * inv;
        p.z = __expf(v1.z) * inv; p.w = __expf(v1.w) * inv;
        prow4[t + 512] = p;
        return;
    }

    // ---------------- match: thread t owns rows t and t+512 -------------------
    {   // stage all keys into LDS (coalesced 16B loads) + init tables
        const float4* kg4 = (const float4*)keys_g;
        float4* kb4 = (float4*)keybuf;
        #pragma unroll
        for (int i = 0; i < 8; ++i) kb4[t + i * 512] = kg4[t + i * 512];
        #pragma unroll
        for (int i = 0; i < 8; ++i) colbest[t + i * 512] = 0ull;
        if (t < 128) coldone[t] = 0u;
        if (t < 32) rowdone[t] = 0u;
        if (t == 0) nleft = 0;
    }
    __syncthreads();   // keys + zeroing visible before atomics below

    int r0 = t, r1 = t + 512;
    int c0f = cont[r0], c1f = cont[r1];
    int p0 = prev[r0], p1 = prev[r1];
    act[r0] = c0f ? (float)p0 : -1.0f;
    act[r1] = c1f ? (float)p1 : -1.0f;
    if (c0f) {
        atomicOr(&rowdone[r0 >> 5], 1u << (r0 & 31));
        atomicOr(&coldone[p0 >> 5], 1u << (p0 & 31));
    }
    if (c1f) {
        atomicOr(&rowdone[r1 >> 5], 1u << (r1 & 31));
        atomicOr(&coldone[p1 >> 5], 1u << (p1 & 31));
    }
    bool act0 = (c0f == 0), act1 = (c1f == 0);

    const u64* kb0 = keybuf + (size_t)r0 * KCAP;   // LDS pointers
    const u64* kb1 = keybuf + (size_t)r1 * KCAP;
    u32 m0 = 0u, m1 = 0u;                          // alive masks (registers)
    #pragma unroll
    for (int k = 0; k < KCAP; ++k) {
        if (kb0[k] != 0ull) m0 |= 1u << k;
        if (kb1[k] != 0ull) m1 |= 1u << k;
    }
    if (m0 == 0u) act0 = false;                    // empty prefix -> fallback
    if (m1 == 0u) act1 = false;
    __syncthreads();

    for (int round = 1; round < 500; ++round) {
        u64 tag = (u64)round << 54;
        bool sub0 = false, sub1 = false;
        u64 best0 = 0ull, best1 = 0ull;
        if (act0) {
            u32 m = m0;
            #pragma unroll
            for (int k = 0; k < KCAP; ++k) {
                if (m & (1u << k)) {
                    u64 kk = kb0[k];
                    int c = key_col(kk);
                    if ((coldone[c >> 5] >> (c & 31)) & 1u) m &= ~(1u << k);
                    else {
                        best0 = umax64(best0, kk);
                        atomicMax((u64*)&colbest[c], tag | kk);
                    }
                }
            }
            m0 = m;
            if (best0 == 0ull) act0 = false;       // exhausted -> fallback later
            else sub0 = true;
        }
        if (act1) {
            u32 m = m1;
            #pragma unroll
            for (int k = 0; k < KCAP; ++k) {
                if (m & (1u << k)) {
                    u64 kk = kb1[k];
                    int c = key_col(kk);
                    if ((coldone[c >> 5] >> (c & 31)) & 1u) m &= ~(1u << k);
                    else {
                        best1 = umax64(best1, kk);
                        atomicMax((u64*)&colbest[c], tag | kk);
                    }
                }
            }
            m1 = m;
            if (best1 == 0ull) act1 = false;
            else sub1 = true;
        }
        __syncthreads();                           // submissions visible
        if (sub0 && colbest[key_col(best0)] == (tag | best0)) {
            int c = key_col(best0);
            act[r0] = (float)c;
            atomicOr(&coldone[c >> 5], 1u << (c & 31));
            atomicOr(&rowdone[r0 >> 5], 1u << (r0 & 31));
            act0 = false;
        }
        if (sub1 && colbest[key_col(best1)] == (tag | best1)) {
            int c = key_col(best1);
            act[r1] = (float)c;
            atomicOr(&coldone[c >> 5], 1u << (c & 31));
            atomicOr(&rowdone[r1 >> 5], 1u << (r1 & 31));
            act1 = false;
        }
        int left = __syncthreads_count((act0 || act1) ? 1 : 0);  // commits visible
        if (left == 0) break;
    }
    __syncthreads();

    // ---- exact-greedy fallback over a COLLECTED list of unmatched rows -------
    if (!((rowdone[r0 >> 5] >> (r0 & 31)) & 1u)) {
        int i = atomicAdd(&nleft, 1); if (i < 64) leftrows[i] = (u32)r0;
    }
    if (!((rowdone[r1 >> 5] >> (r1 & 31)) & 1u)) {
        int i = atomicAdd(&nleft, 1); if (i < 64) leftrows[i] = (u32)r1;
    }
    __syncthreads();
    int nl = nleft;
    if (nl > 0 && nl <= 64 && t < 64) {        // nl>64 (never): full-scan handles
        for (int guard = 0; guard < 100; ++guard) {
            u64 best = 0ull;
            for (int i = 0; i < nl; ++i) {
                int rr = (int)leftrows[i];
                if ((rowdone[rr >> 5] >> (rr & 31)) & 1u) continue;
                const float* srow = s + (size_t)rr * NCOLS;
                u64 rp = (u64)(MROWS - 1 - rr) << 12;
                for (int c = t; c < NCOLS; c += 64) {
                    if ((coldone[c >> 5] >> (c & 31)) & 1u) continue;
                    u64 kk2 = ((u64)fkey(__float_as_uint(srow[c])) << 22) | rp |
                              (u64)(NCOLS - 1 - c);
                    best = umax64(best, kk2);
                }
            }
            best = wave_max_u64(best);
            if (best == 0ull) break;
            if (t == 0) {
                int row = key_row(best), col = key_col(best);
                rowdone[row >> 5] |= 1u << (row & 31);
                coldone[col >> 5] |= 1u << (col & 31);
                act[row] = (float)col;
            }
            WAVE_FENCE();
        }
    }
    __syncthreads();

    // ---- full-scan safety net (no-op when everything matched) ----------------
    if (t < 64) {
        u32 miss = (t < 32) ? ~rowdone[t] : 0u;
        if (__ballot(miss != 0u) != 0ull) {
            for (int guard = 0; guard < 1200; ++guard) {
                u64 best = 0ull;
                for (int rr = 0; rr < MROWS; ++rr) {
                    if ((rowdone[rr >> 5] >> (rr & 31)) & 1u) continue;
                    const float* srow = s + (size_t)rr * NCOLS;
                    u64 rp = (u64)(MROWS - 1 - rr) << 12;
                    for (int c = t; c < NCOLS; c += 64) {
                        if ((coldone[c >> 5] >> (c & 31)) & 1u) continue;
                        u64 kk2 = ((u64)fkey(__float_as_uint(srow[c])) << 22) | rp |
                                  (u64)(NCOLS - 1 - c);
                        best = umax64(best, kk2);
                    }
                }
                best = wave_max_u64(best);
                if (best == 0ull) break;
                if (t == 0) {
                    int row = key_row(best), col = key_col(best);
                    rowdone[row >> 5] |= 1u << (row & 31);
                    coldone[col >> 5] |= 1u << (col & 31);
                    act[row] = (float)col;
                }
                WAVE_FENCE();
            }
        }
    }
    __syncthreads();
    actions[t] = act[t];
    actions[t + 512] = act[t + 512];
}

extern "C" void kernel_launch(void* const* d_in, const int* in_sizes, int n_in,
                              void* d_out, int out_size, void* d_ws, size_t ws_size,
                              hipStream_t stream) {
    (void)in_sizes; (void)n_in; (void)out_size; (void)ws_size;
    const float* scores = (const float*)d_in[0];
    const int* cont = (const int*)d_in[1];
    const int* prev = (const int*)d_in[2];
    float* out = (float*)d_out;
    float* actions = out;
    float* policy = out + MROWS;

    char* ws = (char*)d_ws;
    float* rowsum = (float*)(ws + 0);            // 1024 f
    u64* keys8 = (u64*)(ws + 8192);              // 1024*8 u64 = 64 KiB

    k_prep<<<MROWS / 4, 256, 0, stream>>>(scores, rowsum, keys8);
    k_policy_match<<<MROWS + 1, 512, 0, stream>>>(scores, cont, prev, rowsum,
                                                  keys8, policy, actions);
}

// Round 14
// 101.504 us; speedup vs baseline: 4.7033x; 4.7033x over previous
//
#include <hip/hip_runtime.h>
#include <cstdint>
#include <cstddef>

#define MROWS 1024
#define NCOLS 4096
#define KCAP 12

typedef unsigned long long u64;
typedef unsigned int u32;

// Order-preserving float->u32 map (total order, matches score order exactly).
__device__ inline u32 fkey(u32 b) { return (b & 0x80000000u) ? ~b : (b | 0x80000000u); }

// key = (ord << 22) | ((1023-row) << 12) | (4095-col)   (54 bits used)
__device__ inline int key_col(u64 k) { return (NCOLS - 1) - (int)(k & 0xFFFull); }
__device__ inline int key_row(u64 k) { return (MROWS - 1) - (int)((k >> 12) & 0x3FFull); }

// single-wave LDS ordering fence: wait LDS only, do NOT drain vmcnt
#define WAVE_FENCE() __asm__ volatile("s_waitcnt lgkmcnt(0)" ::: "memory")

__device__ inline float wave_sum_f(float v) {
    #pragma unroll
    for (int off = 32; off >= 1; off >>= 1)
        v += __shfl_xor(v, off, 64);
    return v;
}
__device__ inline u64 wave_max_u64(u64 v) {
    #pragma unroll
    for (int off = 32; off >= 1; off >>= 1) {
        u64 o = __shfl_xor(v, off, 64);
        v = o > v ? o : v;
    }
    return v;
}
__device__ inline u64 umax64(u64 a, u64 b) { return a > b ? a : b; }

// ---------------- K1: per-row threshold key-set + exp-sum ---------------------
// Wave-per-row, ZERO block barriers, 256 workgroups (proven ~7us). {keys:
// score > T} is an exact prefix of the row's descending key order for any T.
// KCAP=12 (keys live in LDS in K2 -- no register-spill exposure; 12 keys/row
// drops exhaustion to ~3-8 rows vs KCAP=8's ~40, which was the REAL 416us:
// the old fallback cost ~10us per exhausted-row pick). Ladder 2.85/3.1/3.4/3.8
// (count monotone in T; ~12% rows retry once, L2-hot). E[count@2.85] ~ 9.
__global__ __launch_bounds__(256, 4) void k_prep(const float* __restrict__ s,
                                                 float* __restrict__ rowsum,
                                                 u64* __restrict__ keys_g) {
    __shared__ u64 list[4][KCAP];
    __shared__ u32 cnts[4];
    int w = threadIdx.x >> 6, lane = threadIdx.x & 63;
    int r = blockIdx.x * 4 + w;

    const float4* s4 = (const float4*)(s + (size_t)r * NCOLS);
    u64 rowpart = (u64)(MROWS - 1 - r) << 12;
    if (lane == 0) cnts[w] = 0u;
    WAVE_FENCE();

    float acc = 0.0f;
    #pragma unroll
    for (int j = 0; j < 16; ++j) {
        float4 v = s4[lane + j * 64];
        acc += __expf(v.x) + __expf(v.y) + __expf(v.z) + __expf(v.w);
        int c0 = 4 * (lane + j * 64);
        if (v.x > 2.85f) { u32 sl = atomicAdd(&cnts[w], 1u); if (sl < KCAP)
            list[w][sl] = ((u64)fkey(__float_as_uint(v.x)) << 22) | rowpart | (u64)(NCOLS - 1 - (c0 + 0)); }
        if (v.y > 2.85f) { u32 sl = atomicAdd(&cnts[w], 1u); if (sl < KCAP)
            list[w][sl] = ((u64)fkey(__float_as_uint(v.y)) << 22) | rowpart | (u64)(NCOLS - 1 - (c0 + 1)); }
        if (v.z > 2.85f) { u32 sl = atomicAdd(&cnts[w], 1u); if (sl < KCAP)
            list[w][sl] = ((u64)fkey(__float_as_uint(v.z)) << 22) | rowpart | (u64)(NCOLS - 1 - (c0 + 2)); }
        if (v.w > 2.85f) { u32 sl = atomicAdd(&cnts[w], 1u); if (sl < KCAP)
            list[w][sl] = ((u64)fkey(__float_as_uint(v.w)) << 22) | rowpart | (u64)(NCOLS - 1 - (c0 + 3)); }
    }
    acc = wave_sum_f(acc);
    if (lane == 0) rowsum[r] = acc;
    WAVE_FENCE();
    u32 n = cnts[w];

    for (int att = 1; att < 4; ++att) {
        if (n <= KCAP) break;
        float T = att == 1 ? 3.1f : att == 2 ? 3.4f : 3.8f;
        if (lane == 0) cnts[w] = 0u;
        WAVE_FENCE();
        #pragma unroll 4
        for (int j = 0; j < 16; ++j) {
            float4 v = s4[lane + j * 64];
            int c0 = 4 * (lane + j * 64);
            if (v.x > T) { u32 sl = atomicAdd(&cnts[w], 1u); if (sl < KCAP)
                list[w][sl] = ((u64)fkey(__float_as_uint(v.x)) << 22) | rowpart | (u64)(NCOLS - 1 - (c0 + 0)); }
            if (v.y > T) { u32 sl = atomicAdd(&cnts[w], 1u); if (sl < KCAP)
                list[w][sl] = ((u64)fkey(__float_as_uint(v.y)) << 22) | rowpart | (u64)(NCOLS - 1 - (c0 + 1)); }
            if (v.z > T) { u32 sl = atomicAdd(&cnts[w], 1u); if (sl < KCAP)
                list[w][sl] = ((u64)fkey(__float_as_uint(v.z)) << 22) | rowpart | (u64)(NCOLS - 1 - (c0 + 2)); }
            if (v.w > T) { u32 sl = atomicAdd(&cnts[w], 1u); if (sl < KCAP)
                list[w][sl] = ((u64)fkey(__float_as_uint(v.w)) << 22) | rowpart | (u64)(NCOLS - 1 - (c0 + 3)); }
        }
        WAVE_FENCE();
        n = cnts[w];
    }
    if (n > KCAP) n = 0;               // ladder failed (adversarial): empty prefix
    if (lane < KCAP)
        keys_g[(size_t)r * KCAP + lane] = (lane < n) ? list[w][lane] : 0ull;
}

// ---------------- K2: block 0 = match (keys in LDS); rest = policy ------------
// Match (r13 structure, spill-proof): keys in LDS keybuf, per-thread state =
// 12-bit alive masks + scalars. Dominant-edge rounds, 512 thr x 2 rows; submit
// ALL alive keys; commit when row-best == col-best; colbest tagged by round.
// Fallback REPLACED (the actual 416us cost in r12/r13): block-cooperative
// candidate scan + wave-0 lazy-invalidation greedy -- same pick sequence as
// the old full rescans (each pick = max over undone rows x free cols) at
// ~1/100 the cost.
__global__ __launch_bounds__(512, 1) void k_policy_match(const float* __restrict__ s,
                                                         const int* __restrict__ cont,
                                                         const int* __restrict__ prev,
                                                         const float* __restrict__ rowsum,
                                                         const u64* __restrict__ keys_g,
                                                         float* __restrict__ policy,
                                                         float* __restrict__ actions) {
    __shared__ u64 keybuf[MROWS * KCAP];       // 96 KiB (match only, RO)
    __shared__ u64 colbest[NCOLS];             // 32 KiB (match only)
    __shared__ u64 cand[64];                   // 512 B fallback candidates
    __shared__ u32 coldone[NCOLS / 32];        // 512 B
    __shared__ u32 rowdone[MROWS / 32];        // 128 B
    __shared__ float act[MROWS];               // 4 KiB
    __shared__ u32 leftrows[64];
    __shared__ int nleft;
    __shared__ float fredf[8];

    int t = threadIdx.x;
    int wid = t >> 6, lane = t & 63;

    if (blockIdx.x != 0) {
        // ---------------- policy row write (512 thr, 2 float4/thr) ------------
        int r = blockIdx.x - 1;
        const float4* srow4 = (const float4*)(s + (size_t)r * NCOLS);
        float4 v0 = srow4[t], v1 = srow4[t + 512];   // fly during the reduce
        float sv = rowsum[t] + rowsum[t + 512];
        sv = wave_sum_f(sv);
        if (lane == 0) fredf[wid] = sv;
        __syncthreads();
        float g = 0.0f;
        #pragma unroll
        for (int i = 0; i < 8; ++i) g += fredf[i];   // same order every block
        float inv = 1.0f / g;
        float4* prow4 = (float4*)(policy + (size_t)r * NCOLS);
        float4 p;
        p.x = __expf(v0.x) * inv; p.y = __expf(v0.y) * inv;
        p.z = __expf(v0.z) * inv; p.w = __expf(v0.w) * inv;
        prow4[t] = p;
        p.x = __expf(v1.x) * inv; p.y = __expf(v1.y) * inv;
        p.z = __expf(v1.z) * inv; p.w = __expf(v1.w) * inv;
        prow4[t + 512] = p;
        return;
    }

    // ---------------- match: thread t owns rows t and t+512 -------------------
    {   // stage all keys into LDS (coalesced 16B loads) + init tables
        const float4* kg4 = (const float4*)keys_g;
        float4* kb4 = (float4*)keybuf;
        #pragma unroll
        for (int i = 0; i < 12; ++i) kb4[t + i * 512] = kg4[t + i * 512];  // 6144
        #pragma unroll
        for (int i = 0; i < 8; ++i) colbest[t + i * 512] = 0ull;
        if (t < 128) coldone[t] = 0u;
        if (t < 64) cand[t] = 0ull;
        if (t < 32) rowdone[t] = 0u;
        if (t == 0) nleft = 0;
    }
    __syncthreads();   // keys + zeroing visible before atomics below

    int r0 = t, r1 = t + 512;
    int c0f = cont[r0], c1f = cont[r1];
    int p0 = prev[r0], p1 = prev[r1];
    act[r0] = c0f ? (float)p0 : -1.0f;
    act[r1] = c1f ? (float)p1 : -1.0f;
    if (c0f) {
        atomicOr(&rowdone[r0 >> 5], 1u << (r0 & 31));
        atomicOr(&coldone[p0 >> 5], 1u << (p0 & 31));
    }
    if (c1f) {
        atomicOr(&rowdone[r1 >> 5], 1u << (r1 & 31));
        atomicOr(&coldone[p1 >> 5], 1u << (p1 & 31));
    }
    bool act0 = (c0f == 0), act1 = (c1f == 0);

    const u64* kb0 = keybuf + (size_t)r0 * KCAP;   // LDS pointers
    const u64* kb1 = keybuf + (size_t)r1 * KCAP;
    u32 m0 = 0u, m1 = 0u;                          // alive masks (registers)
    #pragma unroll
    for (int k = 0; k < KCAP; ++k) {
        if (kb0[k] != 0ull) m0 |= 1u << k;
        if (kb1[k] != 0ull) m1 |= 1u << k;
    }
    if (m0 == 0u) act0 = false;                    // empty prefix -> fallback
    if (m1 == 0u) act1 = false;
    __syncthreads();

    for (int round = 1; round < 500; ++round) {
        u64 tag = (u64)round << 54;
        bool sub0 = false, sub1 = false;
        u64 best0 = 0ull, best1 = 0ull;
        if (act0) {
            u32 m = m0;
            #pragma unroll
            for (int k = 0; k < KCAP; ++k) {
                if (m & (1u << k)) {
                    u64 kk = kb0[k];
                    int c = key_col(kk);
                    if ((coldone[c >> 5] >> (c & 31)) & 1u) m &= ~(1u << k);
                    else {
                        best0 = umax64(best0, kk);
                        atomicMax((u64*)&colbest[c], tag | kk);
                    }
                }
            }
            m0 = m;
            if (best0 == 0ull) act0 = false;       // exhausted -> fallback later
            else sub0 = true;
        }
        if (act1) {
            u32 m = m1;
            #pragma unroll
            for (int k = 0; k < KCAP; ++k) {
                if (m & (1u << k)) {
                    u64 kk = kb1[k];
                    int c = key_col(kk);
                    if ((coldone[c >> 5] >> (c & 31)) & 1u) m &= ~(1u << k);
                    else {
                        best1 = umax64(best1, kk);
                        atomicMax((u64*)&colbest[c], tag | kk);
                    }
                }
            }
            m1 = m;
            if (best1 == 0ull) act1 = false;
            else sub1 = true;
        }
        __syncthreads();                           // submissions visible
        if (sub0 && colbest[key_col(best0)] == (tag | best0)) {
            int c = key_col(best0);
            act[r0] = (float)c;
            atomicOr(&coldone[c >> 5], 1u << (c & 31));
            atomicOr(&rowdone[r0 >> 5], 1u << (r0 & 31));
            act0 = false;
        }
        if (sub1 && colbest[key_col(best1)] == (tag | best1)) {
            int c = key_col(best1);
            act[r1] = (float)c;
            atomicOr(&coldone[c >> 5], 1u << (c & 31));
            atomicOr(&rowdone[r1 >> 5], 1u << (r1 & 31));
            act1 = false;
        }
        int left = __syncthreads_count((act0 || act1) ? 1 : 0);  // commits visible
        if (left == 0) break;
    }
    __syncthreads();

    // ---- fallback: collect unmatched rows ------------------------------------
    if (!((rowdone[r0 >> 5] >> (r0 & 31)) & 1u)) {
        int i = atomicAdd(&nleft, 1); if (i < 64) leftrows[i] = (u32)r0;
    }
    if (!((rowdone[r1 >> 5] >> (r1 & 31)) & 1u)) {
        int i = atomicAdd(&nleft, 1); if (i < 64) leftrows[i] = (u32)r1;
    }
    __syncthreads();
    int nl = nleft; if (nl > 64) nl = 64;
    if (nl > 0) {
        // block-cooperative initial candidate scan: thread t covers 8 cols/row
        for (int i = 0; i < nl; ++i) {
            int rr = (int)leftrows[i];
            const float* srow = s + (size_t)rr * NCOLS;
            u64 rp = (u64)(MROWS - 1 - rr) << 12;
            u64 b = 0ull;
            #pragma unroll
            for (int j = 0; j < 8; ++j) {
                int c = t + j * 512;
                if (!((coldone[c >> 5] >> (c & 31)) & 1u))
                    b = umax64(b, ((u64)fkey(__float_as_uint(srow[c])) << 22) | rp |
                                  (u64)(NCOLS - 1 - c));
            }
            b = wave_max_u64(b);
            if (lane == 0 && b != 0ull) atomicMax((u64*)&cand[i], b);
        }
        __syncthreads();
        // wave-0 lazy-invalidation greedy: candidate only rescanned when its
        // column was taken (max over untaken options is otherwise unchanged).
        if (t < 64) {
            for (int guard = 0; guard < 96; ++guard) {
                for (int i = 0; i < nl; ++i) {
                    int rr = (int)leftrows[i];
                    if ((rowdone[rr >> 5] >> (rr & 31)) & 1u) continue;
                    u64 cd = cand[i];
                    int cc = key_col(cd);
                    if (cd != 0ull && !((coldone[cc >> 5] >> (cc & 31)) & 1u)) continue;
                    const float* srow = s + (size_t)rr * NCOLS;   // wave rescan
                    u64 rp = (u64)(MROWS - 1 - rr) << 12;
                    u64 b = 0ull;
                    for (int c = lane; c < NCOLS; c += 64)
                        if (!((coldone[c >> 5] >> (c & 31)) & 1u))
                            b = umax64(b, ((u64)fkey(__float_as_uint(srow[c])) << 22) | rp |
                                          (u64)(NCOLS - 1 - c));
                    b = wave_max_u64(b);
                    if (lane == 0) cand[i] = b;
                    WAVE_FENCE();
                }
                u64 best = 0ull;
                for (int i = lane; i < nl; i += 64) {
                    int rr = (int)leftrows[i];
                    if (!((rowdone[rr >> 5] >> (rr & 31)) & 1u))
                        best = umax64(best, cand[i]);
                }
                best = wave_max_u64(best);
                if (best == 0ull) break;
                if (lane == 0) {
                    int row = key_row(best), col = key_col(best);
                    rowdone[row >> 5] |= 1u << (row & 31);
                    coldone[col >> 5] |= 1u << (col & 31);
                    act[row] = (float)col;
                }
                WAVE_FENCE();
            }
        }
    }
    __syncthreads();

    // ---- full-scan safety net (no-op when everything matched) ----------------
    if (t < 64) {
        u32 miss = (t < 32) ? ~rowdone[t] : 0u;
        if (__ballot(miss != 0u) != 0ull) {
            for (int guard = 0; guard < 1200; ++guard) {
                u64 best = 0ull;
                for (int rr = 0; rr < MROWS; ++rr) {
                    if ((rowdone[rr >> 5] >> (rr & 31)) & 1u) continue;
                    const float* srow = s + (size_t)rr * NCOLS;
                    u64 rp = (u64)(MROWS - 1 - rr) << 12;
                    for (int c = t; c < NCOLS; c += 64) {
                        if ((coldone[c >> 5] >> (c & 31)) & 1u) continue;
                        u64 kk2 = ((u64)fkey(__float_as_uint(srow[c])) << 22) | rp |
                                  (u64)(NCOLS - 1 - c);
                        best = umax64(best, kk2);
                    }
                }
                best = wave_max_u64(best);
                if (best == 0ull) break;
                if (t == 0) {
                    int row = key_row(best), col = key_col(best);
                    rowdone[row >> 5] |= 1u << (row & 31);
                    coldone[col >> 5] |= 1u << (col & 31);
                    act[row] = (float)col;
                }
                WAVE_FENCE();
            }
        }
    }
    __syncthreads();
    actions[t] = act[t];
    actions[t + 512] = act[t + 512];
}

extern "C" void kernel_launch(void* const* d_in, const int* in_sizes, int n_in,
                              void* d_out, int out_size, void* d_ws, size_t ws_size,
                              hipStream_t stream) {
    (void)in_sizes; (void)n_in; (void)out_size; (void)ws_size;
    const float* scores = (const float*)d_in[0];
    const int* cont = (const int*)d_in[1];
    const int* prev = (const int*)d_in[2];
    float* out = (float*)d_out;
    float* actions = out;
    float* policy = out + MROWS;

    char* ws = (char*)d_ws;
    float* rowsum = (float*)(ws + 0);            // 1024 f
    u64* keys12 = (u64*)(ws + 8192);             // 1024*12 u64 = 96 KiB

    k_prep<<<MROWS / 4, 256, 0, stream>>>(scores, rowsum, keys12);
    k_policy_match<<<MROWS + 1, 512, 0, stream>>>(scores, cont, prev, rowsum,
                                                  keys12, policy, actions);
}